// Round 1
// baseline (168.909 us; speedup 1.0000x reference)
//
#include <hip/hip_runtime.h>
#include <cmath>

#define HW   35200          // 200*176
#define CD   128            // C*D

// ---- workspace float offsets ----
#define OFF_W1F   0         // w1ft[c][o]   64*64
#define OFF_TD    4096      // tD[o][d]     64*2
#define OFF_TH    4224      // tH[o][h]     64*200
#define OFF_TW    17024     // tW[o][w]     64*176
#define OFF_W2F   28288     // w2ft[c][o2]  64*32
#define OFF_B2F   30336     // 32
#define OFF_W3F   30368     // 32
#define OFF_B3    30400     // 1
#define OFF_F1    30720     // f1 [n][32][HW][4]  (18,022,400 floats)

struct Smem {
  float h1[2][64][64];
  float h2[2][32][64];
  float lg[2][64];
  float wt[2][64];
};

__device__ __forceinline__ float lrelu(float v) { return v >= 0.f ? v : 0.01f * v; }

// ---------------- setup: fold BN into weights, build separable PE tables ----------------
__global__ void setup_kernel(const float* __restrict__ w1, const float* __restrict__ b1,
                             const float* __restrict__ g1, const float* __restrict__ be1,
                             const float* __restrict__ w2, const float* __restrict__ b2,
                             const float* __restrict__ g2, const float* __restrict__ be2,
                             const float* __restrict__ w3, const float* __restrict__ b3,
                             float* __restrict__ ws) {
  const float RS = rsqrtf(1.0f + 1e-5f);
  int i = blockIdx.x * blockDim.x + threadIdx.x;
  if (i < 4096) {                       // w1ft[c][o] = w1[o][c] * s1[o]
    int c = i >> 6, o = i & 63;
    ws[OFF_W1F + i] = w1[o*112 + c] * (g1[o] * RS);
    return;
  }
  i -= 4096;
  if (i < 128) {                        // tD[o][d] = s1*(b1 + w1[64..79]·encD(d)) + be1
    int o = i >> 1, d = i & 1;
    float a = 0.f;
    for (int j = 0; j < 8; ++j) {
      float dv = expf((float)(2*j) * (-0.5756462732485115f));
      float t  = (float)d * dv;
      a += w1[o*112 + 64 + j] * sinf(t) + w1[o*112 + 72 + j] * cosf(t);
    }
    ws[OFF_TD + i] = (g1[o]*RS) * (b1[o] + a) + be1[o];
    return;
  }
  i -= 128;
  if (i < 12800) {                      // tH[o][h] = s1 * w1[80..95]·encH(h)
    int o = i / 200, h = i - o*200;
    float a = 0.f;
    for (int j = 0; j < 8; ++j) {
      float dv = expf((float)(2*j) * (-0.5756462732485115f));
      float t  = (float)h * dv;
      a += w1[o*112 + 80 + j] * sinf(t) + w1[o*112 + 88 + j] * cosf(t);
    }
    ws[OFF_TH + i] = (g1[o]*RS) * a;
    return;
  }
  i -= 12800;
  if (i < 11264) {                      // tW[o][w] = s1 * w1[96..111]·encW(w)
    int o = i / 176, w = i - o*176;
    float a = 0.f;
    for (int j = 0; j < 8; ++j) {
      float dv = expf((float)(2*j) * (-0.5756462732485115f));
      float t  = (float)w * dv;
      a += w1[o*112 + 96 + j] * sinf(t) + w1[o*112 + 104 + j] * cosf(t);
    }
    ws[OFF_TW + i] = (g1[o]*RS) * a;
    return;
  }
  i -= 11264;
  if (i < 2048) {                       // w2ft[c][o2] = w2[o2][c] * s2[o2]
    int c = i >> 5, o = i & 31;
    ws[OFF_W2F + i] = w2[o*64 + c] * (g2[o] * RS);
    return;
  }
  i -= 2048;
  if (i < 32) { ws[OFF_B2F + i] = b2[i]*(g2[i]*RS) + be2[i]; return; }
  i -= 32;
  if (i < 32) { ws[OFF_W3F + i] = w3[i]; return; }
  i -= 32;
  if (i == 0) { ws[OFF_B3] = b3[0]; }
}

// ---------------- shared dvf core: computes depth weights wt[2][64] for a 64-pixel tile ----------------
__device__ __forceinline__ void dvf_weights(const float* __restrict__ xn,
                                            const float* __restrict__ wtab,
                                            Smem& s, int hw0) {
  const int px  = threadIdx.x & 63;
  const int wid = __builtin_amdgcn_readfirstlane(threadIdx.x >> 6);  // uniform wave id
  const int hw  = hw0 + px;
  const int h   = hw / 176;
  const int w   = hw - h * 176;

  // ---- layer 1: 64 -> 64 (wave computes 16 output channels, lanes = pixels) ----
  const int og = wid * 16;
  float acc[16][2];
#pragma unroll
  for (int oi = 0; oi < 16; ++oi) {
    const int o = og + oi;
    const float thw = wtab[OFF_TH + o*200 + h] + wtab[OFF_TW + o*176 + w];
    acc[oi][0] = wtab[OFF_TD + o*2 + 0] + thw;
    acc[oi][1] = wtab[OFF_TD + o*2 + 1] + thw;
  }
#pragma unroll 4
  for (int c = 0; c < 64; ++c) {
    const float xv0 = xn[(c*2+0)*HW + hw];
    const float xv1 = xn[(c*2+1)*HW + hw];
    const float* wr = wtab + OFF_W1F + c*64 + og;   // wave-uniform -> s_load
#pragma unroll
    for (int oi = 0; oi < 16; ++oi) {
      const float wv = wr[oi];
      acc[oi][0] = fmaf(wv, xv0, acc[oi][0]);
      acc[oi][1] = fmaf(wv, xv1, acc[oi][1]);
    }
  }
#pragma unroll
  for (int oi = 0; oi < 16; ++oi) {
    s.h1[0][og+oi][px] = lrelu(acc[oi][0]);
    s.h1[1][og+oi][px] = lrelu(acc[oi][1]);
  }
  __syncthreads();

  // ---- layer 2: 64 -> 32 (wave computes 8 output channels) ----
  const int o2g = wid * 8;
  float acc2[8][2];
#pragma unroll
  for (int oi = 0; oi < 8; ++oi) {
    acc2[oi][0] = wtab[OFF_B2F + o2g + oi];
    acc2[oi][1] = acc2[oi][0];
  }
#pragma unroll 4
  for (int c = 0; c < 64; ++c) {
    const float a0 = s.h1[0][c][px];
    const float a1 = s.h1[1][c][px];
    const float* wr = wtab + OFF_W2F + c*32 + o2g;  // wave-uniform -> s_load
#pragma unroll
    for (int oi = 0; oi < 8; ++oi) {
      const float wv = wr[oi];
      acc2[oi][0] = fmaf(wv, a0, acc2[oi][0]);
      acc2[oi][1] = fmaf(wv, a1, acc2[oi][1]);
    }
  }
#pragma unroll
  for (int oi = 0; oi < 8; ++oi) {
    s.h2[0][o2g+oi][px] = lrelu(acc2[oi][0]);
    s.h2[1][o2g+oi][px] = lrelu(acc2[oi][1]);
  }
  __syncthreads();

  // ---- layer 3 (32 -> 1) ----
  if (threadIdx.x < 128) {
    const int d = threadIdx.x >> 6;
    const int p = threadIdx.x & 63;
    float a = wtab[OFF_B3];
#pragma unroll
    for (int c = 0; c < 32; ++c)
      a = fmaf(wtab[OFF_W3F + c], s.h2[d][c][p], a);
    s.lg[d][p] = a;
  }
  __syncthreads();

  // ---- softmax over the 2 depths ----
  if (threadIdx.x < 128) {
    const int d = threadIdx.x >> 6;
    const int p = threadIdx.x & 63;
    s.wt[d][p] = 1.f / (1.f + expf(s.lg[1-d][p] - s.lg[d][p]));
  }
  __syncthreads();
}

// ---------------- pass 1: f1 = dvf(x1), stored as [n][cd/4][hw][4] ----------------
__global__ __launch_bounds__(256)
void dvf_f1_kernel(const float* __restrict__ x,
                   const float* __restrict__ wtab,
                   float* __restrict__ f1out) {
  __shared__ Smem s;
  const int n   = blockIdx.y;
  const int hw0 = blockIdx.x * 64;
  const float* xn = x + (size_t)n * CD * HW;
  dvf_weights(xn, wtab, s, hw0);

  const int px  = threadIdx.x & 63;
  const int wid = threadIdx.x >> 6;
  const int hw  = hw0 + px;
  const float w0  = s.wt[0][px];
  const float w1v = s.wt[1][px];
#pragma unroll
  for (int i = 0; i < 8; ++i) {
    const int cd4 = wid*8 + i;
    const int cd0 = cd4*4;          // cd = c*2+d matches x's [c][d] flattening
    float4 v;
    v.x = xn[(cd0+0)*HW + hw] * w0;
    v.y = xn[(cd0+1)*HW + hw] * w1v;
    v.z = xn[(cd0+2)*HW + hw] * w0;
    v.w = xn[(cd0+3)*HW + hw] * w1v;
    *(float4*)(f1out + (((size_t)n*32 + cd4)*HW + hw)*4) = v;
  }
}

// ---------------- pass 2: out = max(dvf(x0), bilinear(rot(f1))) ----------------
__global__ __launch_bounds__(256)
void dvf_align_kernel(const float* __restrict__ x,
                      const float* __restrict__ wtab,
                      const float* __restrict__ f1,
                      const float* __restrict__ tp,
                      float* __restrict__ out) {
  __shared__ Smem s;
  const int n   = blockIdx.y;
  const int hw0 = blockIdx.x * 64;
  const float* xn = x + (size_t)n * CD * HW;
  dvf_weights(xn, wtab, s, hw0);

  const int px  = threadIdx.x & 63;
  const int wid = threadIdx.x >> 6;
  const int hw  = hw0 + px;
  const int h   = hw / 176;
  const int w   = hw - h * 176;
  const float w0  = s.wt[0][px];
  const float w1v = s.wt[1][px];

  // rotated sample position (faithful two-step rotation like the reference)
  const float thp = tp[n*2 + 0], thc = tp[n*2 + 1];
  const float gx = 0.2f + 0.4f * (float)w;
  const float gy = -39.8f + 0.4f * (float)h;
  const float c1 = cosf(thc),  s1v = sinf(thc);
  const float p1x = gx*c1 - gy*s1v;
  const float p1y = gx*s1v + gy*c1;
  const float c2 = cosf(-thp), s2v = sinf(-thp);
  const float p2x = p1x*c2 - p1y*s2v;
  const float p2y = p1x*s2v + p1y*c2;
  const float xi = p2x / 0.05f / 8.f;
  const float yi = (p2y - (-40.f)) / 0.05f / 8.f;

  const float xf = floorf(xi), yf = floorf(yi);
  const int x0i = (int)xf, y0i = (int)yf;
  const int x0c = min(max(x0i,     0), 175);
  const int x1c = min(max(x0i + 1, 0), 175);
  const int y0c = min(max(y0i,     0), 199);
  const int y1c = min(max(y0i + 1, 0), 199);
  const float x0f = (float)x0c, x1f = (float)x1c;
  const float y0f = (float)y0c, y1f = (float)y1c;
  const float wa = (x1f - xi) * (y1f - yi);
  const float wb = (x1f - xi) * (yi - y0f);
  const float wc = (xi - x0f) * (y1f - yi);
  const float wd = (xi - x0f) * (yi - y0f);
  const int ta = y0c*176 + x0c, tb = y1c*176 + x0c;
  const int tc = y0c*176 + x1c, td = y1c*176 + x1c;

#pragma unroll
  for (int i = 0; i < 8; ++i) {
    const int cd4 = wid*8 + i;
    const int cd0 = cd4*4;
    const float* fb = f1 + ((size_t)n*32 + cd4)*HW*4;
    const float4 Ia = *(const float4*)(fb + (size_t)ta*4);
    const float4 Ib = *(const float4*)(fb + (size_t)tb*4);
    const float4 Ic = *(const float4*)(fb + (size_t)tc*4);
    const float4 Id = *(const float4*)(fb + (size_t)td*4);
    float4 sv;
    sv.x = Ia.x*wa + Ib.x*wb + Ic.x*wc + Id.x*wd;
    sv.y = Ia.y*wa + Ib.y*wb + Ic.y*wc + Id.y*wd;
    sv.z = Ia.z*wa + Ib.z*wb + Ic.z*wc + Id.z*wd;
    sv.w = Ia.w*wa + Ib.w*wb + Ic.w*wc + Id.w*wd;

    const float f00 = xn[(cd0+0)*HW + hw] * w0;
    const float f01 = xn[(cd0+1)*HW + hw] * w1v;
    const float f02 = xn[(cd0+2)*HW + hw] * w0;
    const float f03 = xn[(cd0+3)*HW + hw] * w1v;

    float* op = out + ((size_t)n*CD + cd0)*HW + hw;
    op[0]        = fmaxf(f00, sv.x);
    op[HW]       = fmaxf(f01, sv.y);
    op[2*(size_t)HW] = fmaxf(f02, sv.z);
    op[3*(size_t)HW] = fmaxf(f03, sv.w);
  }
}

extern "C" void kernel_launch(void* const* d_in, const int* in_sizes, int n_in,
                              void* d_out, int out_size, void* d_ws, size_t ws_size,
                              hipStream_t stream) {
  const float* x0  = (const float*)d_in[0];
  const float* x1  = (const float*)d_in[1];
  const float* tp  = (const float*)d_in[2];
  const float* w1  = (const float*)d_in[3];
  const float* b1  = (const float*)d_in[4];
  const float* g1  = (const float*)d_in[5];
  const float* be1 = (const float*)d_in[6];
  const float* w2  = (const float*)d_in[7];
  const float* b2  = (const float*)d_in[8];
  const float* g2  = (const float*)d_in[9];
  const float* be2 = (const float*)d_in[10];
  const float* w3  = (const float*)d_in[11];
  const float* b3  = (const float*)d_in[12];
  float* ws = (float*)d_ws;

  setup_kernel<<<119, 256, 0, stream>>>(w1, b1, g1, be1, w2, b2, g2, be2, w3, b3, ws);

  dim3 grid(550, 4);   // 35200/64 chunks x N
  dvf_f1_kernel<<<grid, 256, 0, stream>>>(x1, ws, ws + OFF_F1);
  dvf_align_kernel<<<grid, 256, 0, stream>>>(x0, ws, ws + OFF_F1, tp, (float*)d_out);
}